// Round 1
// baseline (165.488 us; speedup 1.0000x reference)
//
#include <hip/hip_runtime.h>
#include <math.h>

#define NROWS 16384
#define EPS_F 1e-6f

// One wave (64 lanes) per (row, margin). Block = 256 threads = 4 waves = 2 rows.
// CDF(y) = sum_{k=0..y} pmf(k) with pmf recurrence; lanes cover chunks of length
// c = (y+64)>>6, each chunk seeded in LOG space via lgammaf (avoids f32
// underflow poisoning the whole chain: a chunk whose seed underflows can rise
// at most ~e^45 within 63 steps, keeping its terms < 1e-25 << EPS clip).
__global__ __launch_bounds__(256) void gumbel_nb_kernel(
    const float* __restrict__ r,
    const float* __restrict__ p,
    const int*   __restrict__ target,
    float* __restrict__ out)
{
    __shared__ float u_s[4];
    __shared__ float lp_s[4];
    __shared__ float cll[2];

    const int tid  = threadIdx.x;
    const int wave = tid >> 6;
    const int lane = tid & 63;
    const int rm   = blockIdx.x * 4 + wave;   // row-margin id in [0, 32768)
    const int row  = rm >> 1;
    const int j    = rm & 1;

    // Per-(row,margin) parameters — uniform across the wave.
    const float rr = fmaxf(r[2 * row + j], 1e-4f);
    const float p1 = fminf(fmaxf(tanhf(p[2 * row]), 1e-4f), 0.9999f);
    const int   y  = target[2 * row + j];
    const float yf = (float)y;

    const float logp  = logf(p1);
    const float l1mp  = log1pf(-p1);
    const float base  = rr * l1mp - lgammaf(rr);   // shared log-pmf part

    // ---- CDF: chunked across lanes ----
    const int c = (y + 64) >> 6;       // chunk length; 64*c >= y+1
    const int s = lane * c;            // this lane's chunk start
    float acc = 0.0f;
    if (s <= y) {
        const int cnt = min(c, y + 1 - s);   // #terms this lane sums (>=1)
        const float sf = (float)s;
        // log pmf(s), fully in log space
        const float L0 = lgammaf(sf + rr) - lgammaf(sf + 1.0f) + base + sf * logp;
        float pmf = expf(L0);
        acc = pmf;
        float kf = sf + 1.0f;          // k for next term
        float pk = p1 * (sf + rr);     // p * (k-1+r), incremented by p each step
        for (int m = 1; m < cnt; ++m) {
            pmf *= pk * __builtin_amdgcn_rcpf(kf);   // ~1 ulp rcp; 63 steps -> ~6e-6 rel
            acc += pmf;
            pk += p1;
            kf += 1.0f;
        }
    }
    // wave-level sum (64 lanes)
    for (int off = 32; off > 0; off >>= 1)
        acc += __shfl_xor(acc, off, 64);

    if (lane == 0) {
        // log pmf at exactly k=y (stays in log space; magnitude up to ~ -3.8e4)
        const float lpmf_y = lgammaf(yf + rr) - lgammaf(yf + 1.0f) + base + yf * logp;
        u_s[wave]  = fminf(fmaxf(acc, EPS_F), 1.0f - EPS_F);
        lp_s[wave] = lpmf_y;
    }
    __syncthreads();

    // Combine the two margins of each row; 2 rows per block.
    if (tid < 2) {
        const int rrow = blockIdx.x * 2 + tid;
        const float u1  = u_s[2 * tid];
        const float u2  = u_s[2 * tid + 1];
        const float lp1 = lp_s[2 * tid];
        const float lp2 = lp_s[2 * tid + 1];
        const float rho   = fmaxf(p[2 * rrow + 1], 0.0f) + 1.0f;
        const float theta = fmaxf(rho, 1.00001f);
        const float x1 = -logf(u1);               // in (0, ~13.9]
        const float x2 = -logf(u2);
        const float t1 = expf(theta * logf(x1));  // x1^theta
        const float t2 = expf(theta * logf(x2));
        const float logc = -expf(logf(t1 + t2) / theta);  // -(t1+t2)^(1/theta)
        const float ll = lp1 + lp2 + logc;
        cll[tid] = -ll * (1.0f / (float)NROWS);
    }
    __syncthreads();
    if (tid == 0)
        atomicAdd(out, cll[0] + cll[1]);
}

extern "C" void kernel_launch(void* const* d_in, const int* in_sizes, int n_in,
                              void* d_out, int out_size, void* d_ws, size_t ws_size,
                              hipStream_t stream) {
    const float* r      = (const float*)d_in[0];
    const float* p      = (const float*)d_in[1];
    const int*   target = (const int*)d_in[2];
    float* out = (float*)d_out;

    hipMemsetAsync(out, 0, sizeof(float), stream);
    gumbel_nb_kernel<<<NROWS / 2, 256, 0, stream>>>(r, p, target, out);
}

// Round 2
// 77.235 us; speedup vs baseline: 2.1427x; 2.1427x over previous
//
#include <hip/hip_runtime.h>
#include <math.h>

#define NROWS 16384

// Branch-free lgamma for x in (0, ~4200]: push up by 8, Stirling at z = x+8.
// abs err ~1e-6 from f32 rounding; Stirling series err < 3e-8 at z>=8.
__device__ __forceinline__ float lgam(float x) {
    float p = ((x * (x + 1.f)) * ((x + 2.f) * (x + 3.f))) *
              (((x + 4.f) * (x + 5.f)) * ((x + 6.f) * (x + 7.f)));
    float z  = x + 8.f;
    float lz = __logf(z);
    float zi = __builtin_amdgcn_rcpf(z);
    float r  = (z - 0.5f) * lz - z + 0.91893853320467f
             + zi * (0.08333333333f - 0.0027777778f * (zi * zi));
    return r - __logf(p);
}

// One wave per row; lanes 0-31 -> margin 0, lanes 32-63 -> margin 1.
// CDF truncated at K = min(y, mode + 12*sigma + 32); tail mass < ~1e-5,
// negligible vs the 2% output threshold (budget 404 on a ~2e4 mean).
__global__ __launch_bounds__(256) void nb_rows(
    const float* __restrict__ r,
    const float* __restrict__ p,
    const int*   __restrict__ tg,
    float* __restrict__ ws,      // per-row -ll (if non-null)
    float* __restrict__ out)     // atomic fallback
{
    const int tid  = threadIdx.x;
    const int lane = tid & 63;
    const int sl   = lane & 31;   // sub-lane within half-wave
    const int j    = lane >> 5;   // margin
    const int row  = blockIdx.x * 4 + (tid >> 6);

    const float rr = fmaxf(r[2 * row + j], 1e-4f);
    const float p0 = p[2 * row];
    // tanh via exp: 1 - 2/(e^{2x}+1); clip dominates at extremes.
    const float e2 = __expf(2.f * p0);
    const float p1 = fminf(fmaxf(1.f - 2.f * __builtin_amdgcn_rcpf(e2 + 1.f), 1e-4f), 0.9999f);
    const int   y  = tg[2 * row + j];
    const float yf = (float)y;

    const float q1   = 1.f - p1;
    const float logp = __logf(p1);
    const float base = rr * __logf(q1) - lgam(rr);

    // truncation bound (per half-wave uniform)
    const float qi   = __builtin_amdgcn_rcpf(q1);
    const float mode = rr * p1 * qi;
    const float sig  = __fsqrt_rn(rr * p1) * qi;
    const int   K    = (int)fminf(mode + 12.f * sig + 32.f, yf);

    const int c = (K + 32) >> 5;       // 32*c >= K+1
    const int s = sl * c;
    float acc = 0.f;
    if (s <= K) {
        const int   cnt = min(c, K + 1 - s);
        const float sf  = (float)s;
        const float L0  = lgam(sf + rr) - lgam(sf + 1.f) + base + sf * logp;
        float pmf = __expf(L0);        // may underflow to 0: chunk negligible then
        acc = pmf;
        float kf = sf + 1.f;
        float pk = p1 * (sf + rr);
        for (int m = 1; m < cnt; ++m) {
            pmf *= pk * __builtin_amdgcn_rcpf(kf);
            acc += pmf;
            pk += p1;
            kf += 1.f;
        }
    }
    // sum within each half-wave
    acc += __shfl_xor(acc, 1);
    acc += __shfl_xor(acc, 2);
    acc += __shfl_xor(acc, 4);
    acc += __shfl_xor(acc, 8);
    acc += __shfl_xor(acc, 16);

    // exact log-pmf at k=y (log space; uniform within half-wave)
    const float lpy = lgam(yf + rr) - lgam(yf + 1.f) + base + yf * logp;

    const float u_own  = fminf(fmaxf(acc, 1e-6f), 1.f - 1e-6f);
    const float u_oth  = __shfl_xor(u_own, 32);
    const float lp_oth = __shfl_xor(lpy, 32);

    if (lane == 0) {
        const float rho   = fmaxf(p[2 * row + 1], 0.f) + 1.f;
        const float theta = fmaxf(rho, 1.00001f);
        const float x1 = -__logf(u_own);
        const float x2 = -__logf(u_oth);
        const float t1 = __expf(theta * __logf(x1));
        const float t2 = __expf(theta * __logf(x2));
        const float logc = -__expf(__logf(t1 + t2) * __builtin_amdgcn_rcpf(theta));
        const float nll = -(lpy + lp_oth + logc);
        if (ws) ws[row] = nll;
        else    atomicAdd(out, nll * (1.f / (float)NROWS));
    }
}

__global__ __launch_bounds__(1024) void reduce_ws(
    const float* __restrict__ ws, float* __restrict__ out)
{
    __shared__ float sm[16];
    float a = 0.f;
    for (int i = threadIdx.x; i < NROWS; i += 1024) a += ws[i];
    for (int off = 32; off > 0; off >>= 1) a += __shfl_xor(a, off);
    if ((threadIdx.x & 63) == 0) sm[threadIdx.x >> 6] = a;
    __syncthreads();
    if (threadIdx.x < 16) {
        float b = sm[threadIdx.x];
        b += __shfl_xor(b, 1);
        b += __shfl_xor(b, 2);
        b += __shfl_xor(b, 4);
        b += __shfl_xor(b, 8);
        if (threadIdx.x == 0) out[0] = b * (1.f / (float)NROWS);
    }
}

extern "C" void kernel_launch(void* const* d_in, const int* in_sizes, int n_in,
                              void* d_out, int out_size, void* d_ws, size_t ws_size,
                              hipStream_t stream) {
    const float* r  = (const float*)d_in[0];
    const float* p  = (const float*)d_in[1];
    const int*   tg = (const int*)d_in[2];
    float* out = (float*)d_out;

    if (ws_size >= NROWS * sizeof(float)) {
        float* ws = (float*)d_ws;
        nb_rows<<<NROWS / 4, 256, 0, stream>>>(r, p, tg, ws, nullptr);
        reduce_ws<<<1, 1024, 0, stream>>>(ws, out);
    } else {
        hipMemsetAsync(out, 0, sizeof(float), stream);
        nb_rows<<<NROWS / 4, 256, 0, stream>>>(r, p, tg, nullptr, out);
    }
}

// Round 4
// 76.145 us; speedup vs baseline: 2.1733x; 1.0143x over previous
//
#include <hip/hip_runtime.h>
#include <math.h>

#define NROWS 16384

__device__ __forceinline__ float prod8(float x) {
    return ((x * (x + 1.f)) * ((x + 2.f) * (x + 3.f))) *
           (((x + 4.f) * (x + 5.f)) * ((x + 6.f) * (x + 7.f)));
}

// logGamma(x) via push-up-by-8 Stirling; abs err ~1e-5 on (0, 4200]
__device__ __forceinline__ float lgam(float x) {
    float z  = x + 8.f;
    float lz = __logf(z);
    float zi = __builtin_amdgcn_rcpf(z);
    return (z - 0.5f) * lz - z + 0.91893853f + 0.08333333f * zi - __logf(prod8(x));
}

// logGamma(a) - logGamma(b); constant cancels, keep only 1/z Stirling term.
__device__ __forceinline__ float lgam_diff(float a, float b) {
    float za = a + 8.f, zb = b + 8.f;
    float la = __logf(za), lb = __logf(zb);
    float ra = __builtin_amdgcn_rcpf(za), rb = __builtin_amdgcn_rcpf(zb);
    return (za - 0.5f) * la - (zb - 0.5f) * lb - (a - b)
         + 0.08333333f * (ra - rb)
         + __logf(prod8(b) * __builtin_amdgcn_rcpf(prod8(a)));
}

// One full wave per (row, margin): 32768 waves. Block = 256 = 4 waves = 2 rows.
// CDF truncated at K = min(mode + 6*sigma + 16, y); tail mass error <= ~5e-3
// absolute in u (only when u~1) -> logc error ~5e-3/row << 404 budget.
__global__ __launch_bounds__(256) void nb_rows(
    const float* __restrict__ r,
    const float* __restrict__ p,
    const int*   __restrict__ tg,
    float* __restrict__ ws,      // per-row -ll (if non-null)
    float* __restrict__ out)     // atomic fallback
{
    __shared__ float su[4], sv[4];
    const int tid  = threadIdx.x;
    const int w    = tid >> 6;
    const int lane = tid & 63;
    const int rm   = blockIdx.x * 4 + w;   // (row,margin) unit
    const int row  = rm >> 1;
    const int j    = rm & 1;

    const float rr = fmaxf(r[2 * row + j], 1e-4f);
    const float p0 = p[2 * row];
    const float e2 = __expf(2.f * p0);     // tanh via exp
    const float p1 = fminf(fmaxf(1.f - 2.f * __builtin_amdgcn_rcpf(e2 + 1.f), 1e-4f), 0.9999f);
    const int   y  = tg[2 * row + j];
    const float yf = (float)y;

    const float q1   = 1.f - p1;
    const float logp = __logf(p1);
    const float base = rr * __logf(q1) - lgam(rr);

    // truncation bound
    const float qi = __builtin_amdgcn_rcpf(q1);
    const float rp = rr * p1;
    const int   K  = (int)fminf(fmaf(6.f, __fsqrt_rn(rp) * qi, rp * qi) + 16.f, yf);

    const int c = (K + 64) >> 6;           // 64*c >= K+1
    const int s = lane * c;
    float acc = 0.f;
    if (s <= K) {
        const int   cnt = min(c, K + 1 - s);
        const float sf  = (float)s;
        float pmf = __expf(lgam_diff(sf + rr, sf + 1.f) + base + sf * logp);
        acc = pmf;
        float kf = sf + 1.f;
        float pk = p1 * (sf + rr);
        for (int m = 1; m < cnt; ++m) {
            pmf *= pk * __builtin_amdgcn_rcpf(kf);
            acc += pmf;
            pk += p1;
            kf += 1.f;
        }
    }
    #pragma unroll
    for (int off = 32; off; off >>= 1) acc += __shfl_xor(acc, off);

    // exact log-pmf at k=y (log space)
    const float lpy = lgam_diff(yf + rr, yf + 1.f) + base + yf * logp;

    if (lane == 0) {
        su[w] = fminf(fmaxf(acc, 1e-6f), 1.f - 1e-6f);
        sv[w] = lpy;
    }
    __syncthreads();
    if (tid < 2) {
        const int   rrow  = blockIdx.x * 2 + tid;
        const float u1    = su[2 * tid], u2 = su[2 * tid + 1];
        const float theta = fmaxf(fmaxf(p[2 * rrow + 1], 0.f) + 1.f, 1.00001f);
        const float x1 = -__logf(u1);
        const float x2 = -__logf(u2);
        const float t1 = __expf(theta * __logf(x1));
        const float t2 = __expf(theta * __logf(x2));
        const float logc = -__expf(__logf(t1 + t2) * __builtin_amdgcn_rcpf(theta));
        const float nll  = -(sv[2 * tid] + sv[2 * tid + 1] + logc);
        if (ws) ws[rrow] = nll;
        else    atomicAdd(out, nll * (1.f / (float)NROWS));
    }
}

__global__ __launch_bounds__(1024) void reduce_ws(
    const float* __restrict__ ws, float* __restrict__ out)
{
    __shared__ float sm[16];
    const int t = threadIdx.x;
    float a0 = 0.f, a1 = 0.f, a2 = 0.f, a3 = 0.f;
    #pragma unroll
    for (int i = 0; i < 4; ++i) {
        const int b = t + i * 4096;
        a0 += ws[b];
        a1 += ws[b + 1024];
        a2 += ws[b + 2048];
        a3 += ws[b + 3072];
    }
    float a = (a0 + a1) + (a2 + a3);
    #pragma unroll
    for (int off = 32; off; off >>= 1) a += __shfl_xor(a, off);
    if ((t & 63) == 0) sm[t >> 6] = a;
    __syncthreads();
    if (t < 16) {
        float b = sm[t];
        b += __shfl_xor(b, 1);
        b += __shfl_xor(b, 2);
        b += __shfl_xor(b, 4);
        b += __shfl_xor(b, 8);
        if (t == 0) out[0] = b * (1.f / (float)NROWS);
    }
}

extern "C" void kernel_launch(void* const* d_in, const int* in_sizes, int n_in,
                              void* d_out, int out_size, void* d_ws, size_t ws_size,
                              hipStream_t stream) {
    const float* r  = (const float*)d_in[0];
    const float* p  = (const float*)d_in[1];
    const int*   tg = (const int*)d_in[2];
    float* out = (float*)d_out;

    if (ws_size >= NROWS * sizeof(float)) {
        float* ws = (float*)d_ws;
        nb_rows<<<2 * NROWS / 4, 256, 0, stream>>>(r, p, tg, ws, nullptr);
        reduce_ws<<<1, 1024, 0, stream>>>(ws, out);
    } else {
        hipMemsetAsync(out, 0, sizeof(float), stream);
        nb_rows<<<2 * NROWS / 4, 256, 0, stream>>>(r, p, tg, nullptr, out);
    }
}